// Round 12
// baseline (206.365 us; speedup 1.0000x reference)
//
#include <hip/hip_runtime.h>
#include <hip/hip_bf16.h>
#include <math.h>

// Problem constants
#define BB 4
#define SS 2048
#define DD 512
#define HH 8
#define DHH 64
#define DFF 2048
#define MM (BB*SS)          // 8192 rows
#define QKV_N (3*DD)        // 1536

typedef float  f32x4  __attribute__((ext_vector_type(4)));
typedef __bf16 bf16x8 __attribute__((ext_vector_type(8)));
typedef unsigned short us8 __attribute__((ext_vector_type(8)));
typedef unsigned short us4 __attribute__((ext_vector_type(4)));

// ---- bf16 helpers (RNE, finite inputs) ----
__device__ __forceinline__ unsigned short f2bf(float v) {
    unsigned int u = __float_as_uint(v);
    unsigned int r = (u + 0x7fffu + ((u >> 16) & 1u)) >> 16;
    return (unsigned short)r;
}
__device__ __forceinline__ float bf2f(unsigned short h) {
    return __uint_as_float(((unsigned int)h) << 16);
}

__device__ __forceinline__ f32x4 mfma_bf16(us8 a, us8 b, f32x4 c) {
    return __builtin_amdgcn_mfma_f32_16x16x32_bf16(
        __builtin_bit_cast(bf16x8, a), __builtin_bit_cast(bf16x8, b), c, 0, 0, 0);
}

// NOTE: imm offset of global_load_lds applies to BOTH global and LDS addresses
// (round-9 NaN post-mortem) — always pass 0 and advance pointers instead.
__device__ __forceinline__ void gload_lds16(const void* gsrc, void* ldst) {
    __builtin_amdgcn_global_load_lds(
        (const __attribute__((address_space(1))) void*)gsrc,
        (__attribute__((address_space(3))) void*)ldst, 16, 0, 0);
}

#define VMC(n) asm volatile("s_waitcnt vmcnt(" #n ")" ::: "memory")

// Split-bf16 global layout: per row of K elements -> K/32 blocks of 128B:
// [32 x bf16 hi][32 x bf16 lo]. ushort index: row*2K + (k/32)*64 + (k%32); lo at +32.

// ---------------------------------------------------------------- LayerNorm -> split bf16
__global__ __launch_bounds__(128)
void ln_kernel(const float* __restrict__ x, const float* __restrict__ g,
               const float* __restrict__ beta, unsigned short* __restrict__ outp)
{
    const int row = blockIdx.x;
    const int t = threadIdx.x;               // 128 threads, 4 floats each
    const float4 v = reinterpret_cast<const float4*>(x + (size_t)row * DD)[t];

    float s  = v.x + v.y + v.z + v.w;
    float s2 = v.x*v.x + v.y*v.y + v.z*v.z + v.w*v.w;
    #pragma unroll
    for (int off = 32; off >= 1; off >>= 1) {
        s  += __shfl_xor(s,  off);
        s2 += __shfl_xor(s2, off);
    }
    __shared__ float red[2][2];
    const int lane = t & 63, wid = t >> 6;
    if (lane == 0) { red[wid][0] = s; red[wid][1] = s2; }
    __syncthreads();
    const float ts  = red[0][0] + red[1][0];
    const float ts2 = red[0][1] + red[1][1];
    const float mu  = ts * (1.0f / DD);
    const float var = ts2 * (1.0f / DD) - mu * mu;
    const float rs  = rsqrtf(var + 1e-5f);

    const float4 gv = reinterpret_cast<const float4*>(g)[t];
    const float4 bv = reinterpret_cast<const float4*>(beta)[t];
    float vals[4];
    vals[0] = (v.x - mu) * rs * gv.x + bv.x;
    vals[1] = (v.y - mu) * rs * gv.y + bv.y;
    vals[2] = (v.z - mu) * rs * gv.z + bv.z;
    vals[3] = (v.w - mu) * rs * gv.w + bv.w;

    us4 hv, lv;
    #pragma unroll
    for (int i = 0; i < 4; ++i) {
        hv[i] = f2bf(vals[i]);
        lv[i] = f2bf(vals[i] - bf2f(hv[i]));
    }
    const int k = t * 4;
    size_t o = (size_t)row * 1024 + (size_t)(k >> 5) * 64 + (k & 31);
    *reinterpret_cast<us4*>(outp + o)      = hv;
    *reinterpret_cast<us4*>(outp + o + 32) = lv;
}

// ---------------------------------------------------------------- fp32 -> split bf16 (all weights)
__global__ __launch_bounds__(256)
void conv_all(const float* __restrict__ w_in, const float* __restrict__ w_out,
              const float* __restrict__ w_ff1, const float* __restrict__ w_ff2,
              unsigned short* __restrict__ dst3, unsigned short* __restrict__ dstw2)
{
    const int gid = blockIdx.x * 256 + threadIdx.x;
    const float* src;
    unsigned short* dst;
    size_t o;
    if (gid < 262144) {
        const int r  = gid >> 6;
        const int k0 = (gid & 63) * 8;
        src = (r < 1536) ? w_in  + (size_t)r * 512 + k0
            : (r < 2048) ? w_out + (size_t)(r - 1536) * 512 + k0
                         : w_ff1 + (size_t)(r - 2048) * 512 + k0;
        o = (size_t)r * 1024 + (size_t)(k0 >> 5) * 64 + (k0 & 31);
        dst = dst3;
    } else {
        const int g  = gid - 262144;
        const int r  = g >> 8;
        const int k0 = (g & 255) * 8;
        src = w_ff2 + (size_t)r * 2048 + k0;
        o = (size_t)r * 4096 + (size_t)(k0 >> 5) * 64 + (k0 & 31);
        dst = dstw2;
    }
    us8 h, l;
    #pragma unroll
    for (int i = 0; i < 8; ++i) {
        float v = src[i];
        h[i] = f2bf(v);
        l[i] = f2bf(v - bf2f(h[i]));
    }
    *reinterpret_cast<us8*>(dst + o)      = h;
    *reinterpret_cast<us8*>(dst + o + 32) = l;
}

// ---------------------------------------------------------------- 8-phase 256x256 split GEMM
// m201-faithful port for split-bf16. 512 thr = 8 waves (2M x 4N); per-wave 128x64 out.
// K-step per iter = 64 elems = 2 K-tiles of 32; LDS = 2 dbuf x (A 32KB + B 32KB) = 128KB.
// Half-tiles: A-half = 128 rows (16KB), B-half = 128 cols. Per phase: ds_reads of one
// C-quadrant + 1 half-tile stage (2 gloads) -> barrier -> lgkmcnt(0) -> 24 MFMA ->
// counted vmcnt(4) at phases 4,8 only (never 0 mid-loop) -> barrier.
// Verified schedule: reads(ph): dbuf0 (A0B0)(A1B0)(A0B1)(A1B1), dbuf1 same at ph5-8.
// stages(ph): 1:A1(t+1) 2:B1(t+1) 3:B0(t+2) 4:A0(t+2) 5:A1(t+2) 6:B1(t+2) 7:B0(t+3) 8:A0(t+3).
// Every read covered by the vmcnt(4)+barrier checkpoint preceding it.
// EPI: 0 = bias -> fp32 Cf; 2 = bias + GELU -> split Cs
#define TRIP(MI, NI, AH, AL, BH, BL)                                              \
    acc[MI][NI] = mfma_bf16(AH, BH, acc[MI][NI]);                                 \
    acc[MI][NI] = mfma_bf16(AH, BL, acc[MI][NI]);                                 \
    acc[MI][NI] = mfma_bf16(AL, BH, acc[MI][NI]);

#define PHASE(D, MH, NH, RB, STG, WAITC) do {                                     \
    const unsigned short* S_ = smem + (D) * 32768;                                \
    us8 ah0_ = *(const us8*)(S_ + aoff[(MH)*4+0]);                                \
    us8 al0_ = *(const us8*)(S_ + (aoff[(MH)*4+0] ^ 32));                         \
    us8 ah1_ = *(const us8*)(S_ + aoff[(MH)*4+1]);                                \
    us8 al1_ = *(const us8*)(S_ + (aoff[(MH)*4+1] ^ 32));                         \
    us8 ah2_ = *(const us8*)(S_ + aoff[(MH)*4+2]);                                \
    us8 al2_ = *(const us8*)(S_ + (aoff[(MH)*4+2] ^ 32));                         \
    us8 ah3_ = *(const us8*)(S_ + aoff[(MH)*4+3]);                                \
    us8 al3_ = *(const us8*)(S_ + (aoff[(MH)*4+3] ^ 32));                         \
    if (RB) {                                                                     \
        bh0 = *(const us8*)(S_ + boff[(NH)*2+0]);                                 \
        bl0 = *(const us8*)(S_ + (boff[(NH)*2+0] ^ 32));                          \
        bh1 = *(const us8*)(S_ + boff[(NH)*2+1]);                                 \
        bl1 = *(const us8*)(S_ + (boff[(NH)*2+1] ^ 32));                          \
    }                                                                             \
    STG;                                                                          \
    __builtin_amdgcn_s_barrier();                                                 \
    asm volatile("s_waitcnt lgkmcnt(0)" ::: "memory");                            \
    __builtin_amdgcn_sched_barrier(0);                                            \
    __builtin_amdgcn_s_setprio(1);                                                \
    TRIP((MH)*4+0, (NH)*2+0, ah0_, al0_, bh0, bl0)                                \
    TRIP((MH)*4+0, (NH)*2+1, ah0_, al0_, bh1, bl1)                                \
    TRIP((MH)*4+1, (NH)*2+0, ah1_, al1_, bh0, bl0)                                \
    TRIP((MH)*4+1, (NH)*2+1, ah1_, al1_, bh1, bl1)                                \
    TRIP((MH)*4+2, (NH)*2+0, ah2_, al2_, bh0, bl0)                                \
    TRIP((MH)*4+2, (NH)*2+1, ah2_, al2_, bh1, bl1)                                \
    TRIP((MH)*4+3, (NH)*2+0, ah3_, al3_, bh0, bl0)                                \
    TRIP((MH)*4+3, (NH)*2+1, ah3_, al3_, bh1, bl1)                                \
    __builtin_amdgcn_s_setprio(0);                                                \
    __builtin_amdgcn_sched_barrier(0);                                            \
    WAITC;                                                                        \
    __builtin_amdgcn_s_barrier();                                                 \
} while (0)

template<int EPI>
__global__ __launch_bounds__(512, 1)
void gemm8(const unsigned short* __restrict__ Ax, const unsigned short* __restrict__ Wx,
           const float* __restrict__ bias,
           float* __restrict__ Cf, unsigned short* __restrict__ Cs,
           int N, int K)
{
    __shared__ unsigned short smem[65536];    // 128 KB: [dbuf][A 16384 | B 16384] ush
    const int tid  = threadIdx.x;
    const int wave = tid >> 6, lane = tid & 63;
    const int wm = wave >> 2, wn = wave & 3;
    const int lr = lane & 15, kc = lane >> 4;

    const int nwg = gridDim.x * gridDim.y;
    int bid = blockIdx.y * gridDim.x + blockIdx.x;
    bid = (bid & 7) * (nwg >> 3) + (bid >> 3);
    const int bnn = (bid % gridDim.x) * 256;
    const int bm  = (bid / gridDim.x) * 256;

    const int K2    = K * 2;
    const int niter = K >> 6;                 // 2 K-tiles per iter

    int aoff[8], boff[4];
    #pragma unroll
    for (int mf = 0; mf < 8; ++mf) {
        const int ra = wm * 128 + mf * 16 + lr;
        aoff[mf] = ra * 64 + ((kc ^ (ra & 7)) * 8);
    }
    #pragma unroll
    for (int nf = 0; nf < 4; ++nf) {
        const int rb = wn * 64 + nf * 16 + lr;
        boff[nf] = 16384 + rb * 64 + ((kc ^ (rb & 7)) * 8);
    }

    f32x4 acc[8][4];
    #pragma unroll
    for (int i = 0; i < 8; ++i)
        #pragma unroll
        for (int j = 0; j < 4; ++j) acc[i][j] = (f32x4){0.f, 0.f, 0.f, 0.f};

    // staging pointers: half h, load j; src chunk = LDS slot ^ (row&7)
    const unsigned short* aPtr[2][2];
    const unsigned short* bPtr[2][2];
    #pragma unroll
    for (int h = 0; h < 2; ++h)
        #pragma unroll
        for (int j = 0; j < 2; ++j) {
            const int off = j * 4096 + tid * 8;      // ush offset within half
            const int row = h * 128 + (off >> 6);
            const int q   = (tid & 7) ^ (row & 7);
            aPtr[h][j] = Ax + (size_t)(bm  + row) * K2 + q * 8;
            bPtr[h][j] = Wx + (size_t)(bnn + row) * K2 + q * 8;
        }

    auto stA = [&](int D, int h) {
        #pragma unroll
        for (int j = 0; j < 2; ++j) {
            gload_lds16(aPtr[h][j], &smem[D * 32768 + h * 8192 + j * 4096 + tid * 8]);
            aPtr[h][j] += 64;                        // next K-tile
        }
    };
    auto stB = [&](int D, int h) {
        #pragma unroll
        for (int j = 0; j < 2; ++j) {
            gload_lds16(bPtr[h][j], &smem[D * 32768 + 16384 + h * 8192 + j * 4096 + tid * 8]);
            bPtr[h][j] += 64;
        }
    };

    // prologue: tile0 full -> dbuf0 (oldest), tile1 A0,B0 -> dbuf1
    stA(0, 0); stA(0, 1); stB(0, 0); stB(0, 1);
    stA(1, 0); stB(1, 0);
    VMC(4);                                          // tile0's 8 loads landed
    __builtin_amdgcn_s_barrier();

    for (int i = 0; i < niter; ++i) {
        const bool more = (i + 1 < niter);
        us8 bh0, bl0, bh1, bl1;
        PHASE(0, 0, 0, 1, { stA(1, 1); }, {});
        PHASE(0, 1, 0, 0, { stB(1, 1); }, {});
        PHASE(0, 0, 1, 1, { if (more) { stB(0, 0); } }, {});
        PHASE(0, 1, 1, 0, { if (more) { stA(0, 0); } },
                          { if (more) { VMC(4); } else { VMC(0); } });
        PHASE(1, 0, 0, 1, { if (more) { stA(0, 1); } }, {});
        PHASE(1, 1, 0, 0, { if (more) { stB(0, 1); } }, {});
        PHASE(1, 0, 1, 1, { if (more) { stB(1, 0); } }, {});
        PHASE(1, 1, 1, 0, { if (more) { stA(1, 0); } }, { VMC(4); });
    }

    // epilogue; C/D layout: col = lane&15, row = (lane>>4)*4 + reg
    float bvn[4];
    #pragma unroll
    for (int nf = 0; nf < 4; ++nf) bvn[nf] = bias[bnn + wn * 64 + nf * 16 + lr];

    #pragma unroll
    for (int mf = 0; mf < 8; ++mf) {
        #pragma unroll
        for (int j = 0; j < 4; ++j) {
            const int row = bm + wm * 128 + mf * 16 + kc * 4 + j;
            #pragma unroll
            for (int nf = 0; nf < 4; ++nf) {
                const int col = bnn + wn * 64 + nf * 16 + lr;
                float v = acc[mf][nf][j] + bvn[nf];
                if constexpr (EPI == 2) {
                    v = 0.5f * v * (1.0f + erff(v * 0.70710678118654752f));
                    unsigned short h = f2bf(v);
                    unsigned short l = f2bf(v - bf2f(h));
                    size_t o = (size_t)row * (size_t)(N * 2) + (size_t)(col >> 5) * 64 + (col & 31);
                    Cs[o]      = h;
                    Cs[o + 32] = l;
                } else {
                    Cf[(size_t)row * N + col] = v;
                }
            }
        }
    }
}

// ---------------------------------------------------------------- BN=64 split GEMM (oproj, FF2)
// Known-good round-11 kernel: 48KB LDS -> 3 blocks/CU, 2-barrier dbuf loop.
template<int BN, int EPI>
__global__ __launch_bounds__(256, 3)
void gemm_tile(const unsigned short* __restrict__ Ax, const unsigned short* __restrict__ Wx,
               const float* __restrict__ bias, const float* __restrict__ Res,
               float* __restrict__ Cf, unsigned short* __restrict__ Cs,
               int N, int K)
{
    constexpr int NF   = BN / 32;
    constexpr int NB   = BN / 32;
    constexpr int AUSH = 128 * 64;
    constexpr int BUSH = BN * 64;
    __shared__ unsigned short smem[2][AUSH + BUSH];

    const int tid  = threadIdx.x;
    const int wave = tid >> 6, lane = tid & 63;
    const int wm = wave >> 1, wn = wave & 1;
    const int lr = lane & 15, kc = lane >> 4;

    const int nwg = gridDim.x * gridDim.y;
    int bid = blockIdx.y * gridDim.x + blockIdx.x;
    bid = (bid & 7) * (nwg >> 3) + (bid >> 3);
    const int bn = (bid % gridDim.x) * BN;
    const int bm = (bid / gridDim.x) * 128;

    const int K2  = K * 2;
    const int nkb = K >> 5;

    int aoff[4], woff[NF];
    #pragma unroll
    for (int m = 0; m < 4; ++m) {
        const int ra = wm * 64 + m * 16 + lr;
        aoff[m] = ra * 64 + ((kc ^ (ra & 7)) * 8);
    }
    #pragma unroll
    for (int n = 0; n < NF; ++n) {
        const int rw = wn * (NF * 16) + n * 16 + lr;
        woff[n] = AUSH + rw * 64 + ((kc ^ (rw & 7)) * 8);
    }

    f32x4 acc[4][NF];
    #pragma unroll
    for (int i = 0; i < 4; ++i)
        #pragma unroll
        for (int j = 0; j < NF; ++j) acc[i][j] = (f32x4){0.f, 0.f, 0.f, 0.f};

    const unsigned short* aP[4];
    const unsigned short* wP[NB];
    #pragma unroll
    for (int j = 0; j < 4; ++j) {
        const int off = j * 2048 + tid * 8;
        const int row = off >> 6;
        const int q   = ((off >> 3) & 7) ^ (row & 7);
        aP[j] = Ax + (size_t)(bm + row) * K2 + q * 8;
    }
    #pragma unroll
    for (int j = 0; j < NB; ++j) {
        const int off = j * 2048 + tid * 8;
        const int row = off >> 6;
        const int q   = ((off >> 3) & 7) ^ (row & 7);
        wP[j] = Wx + (size_t)(bn + row) * K2 + q * 8;
    }

#define STAGE_T(BUF) do {                                                      \
        _Pragma("unroll")                                                      \
        for (int j = 0; j < 4; ++j)                                            \
            gload_lds16(aP[j], &smem[BUF][j * 2048 + tid * 8]);                \
        _Pragma("unroll")                                                      \
        for (int j = 0; j < NB; ++j)                                           \
            gload_lds16(wP[j], &smem[BUF][AUSH + j * 2048 + tid * 8]);         \
    } while (0)

#define ADV_T() do {                                                           \
        _Pragma("unroll")                                                      \
        for (int j = 0; j < 4; ++j) aP[j] += 64;                               \
        _Pragma("unroll")                                                      \
        for (int j = 0; j < NB; ++j) wP[j] += 64;                              \
    } while (0)

#define COMPUTE_T(BUF) do {                                                    \
        const unsigned short* S = smem[BUF];                                   \
        us8 ah[4], al[4], wh[NF], wl[NF];                                      \
        _Pragma("unroll")                                                      \
        for (int m = 0; m < 4; ++m) {                                          \
            ah[m] = *reinterpret_cast<const us8*>(S + aoff[m]);                \
            al[m] = *reinterpret_cast<const us8*>(S + (aoff[m] ^ 32));         \
        }                                                                      \
        _Pragma("unroll")                                                      \
        for (int n = 0; n < NF; ++n) {                                         \
            wh[n] = *reinterpret_cast<const us8*>(S + woff[n]);                \
            wl[n] = *reinterpret_cast<const us8*>(S + (woff[n] ^ 32));         \
        }                                                                      \
        _Pragma("unroll")                                                      \
        for (int m = 0; m < 4; ++m)                                            \
            _Pragma("unroll")                                                  \
            for (int n = 0; n < NF; ++n) {                                     \
                acc[m][n] = mfma_bf16(ah[m], wh[n], acc[m][n]);                \
                acc[m][n] = mfma_bf16(ah[m], wl[n], acc[m][n]);                \
                acc[m][n] = mfma_bf16(al[m], wh[n], acc[m][n]);                \
            }                                                                  \
    } while (0)

    STAGE_T(0); ADV_T();
    for (int kb = 0; kb < nkb; kb += 2) {
        __syncthreads();
        STAGE_T(1); ADV_T();
        COMPUTE_T(0);
        __syncthreads();
        if (kb + 2 < nkb) STAGE_T(0);
        ADV_T();
        COMPUTE_T(1);
    }
#undef STAGE_T
#undef ADV_T
#undef COMPUTE_T

    float bvn[NF];
    #pragma unroll
    for (int n = 0; n < NF; ++n) bvn[n] = bias[bn + wn * (NF * 16) + n * 16 + lr];

    #pragma unroll
    for (int m = 0; m < 4; ++m) {
        #pragma unroll
        for (int j = 0; j < 4; ++j) {
            const int row = bm + wm * 64 + m * 16 + kc * 4 + j;
            #pragma unroll
            for (int n = 0; n < NF; ++n) {
                const int col = bn + wn * (NF * 16) + n * 16 + lr;
                float v = acc[m][n][j] + bvn[n];
                if constexpr (EPI == 1) v += Res[(size_t)row * N + col];
                if constexpr (EPI == 2) {
                    v = 0.5f * v * (1.0f + erff(v * 0.70710678118654752f));
                    unsigned short h = f2bf(v);
                    unsigned short l = f2bf(v - bf2f(h));
                    size_t o = (size_t)row * (size_t)(N * 2) + (size_t)(col >> 5) * 64 + (col & 31);
                    Cs[o]      = h;
                    Cs[o + 32] = l;
                } else {
                    Cf[(size_t)row * N + col] = v;
                }
            }
        }
    }
}

// ---------------------------------------------------------------- Local attention (fp32 in, split out)
__global__ __launch_bounds__(256)
void attn_kernel(const float* __restrict__ qkv, unsigned short* __restrict__ ctx)
{
    constexpr int RAD = 4;
    constexpr int TQ  = 64;
    constexpr int KROWS = TQ + 2 * RAD;   // 72
    constexpr int LDK = DHH + 4;          // 68

    __shared__ float Ks[KROWS][LDK];
    __shared__ float Vs[KROWS][LDK];

    const int t  = threadIdx.x;
    const int qt = blockIdx.x;
    const int b  = blockIdx.y;
    const int h  = blockIdx.z;
    const int q0 = qt * TQ;
    const float* base = qkv + ((size_t)b * SS) * QKV_N + h * DHH;

    for (int idx = t; idx < KROWS * (DHH / 4); idx += 256) {
        const int row = idx >> 4;
        const int c4  = idx & 15;
        const int gr  = q0 - RAD + row;
        float4 kv = make_float4(0.f, 0.f, 0.f, 0.f);
        float4 vv = kv;
        if (gr >= 0 && gr < SS) {
            const float* p = base + (size_t)gr * QKV_N;
            kv = *reinterpret_cast<const float4*>(p + DD     + c4 * 4);
            vv = *reinterpret_cast<const float4*>(p + 2 * DD + c4 * 4);
        }
        *reinterpret_cast<float4*>(&Ks[row][c4 * 4]) = kv;
        *reinterpret_cast<float4*>(&Vs[row][c4 * 4]) = vv;
    }
    __syncthreads();

    const int qi   = t >> 2;
    const int quad = t & 3;
    const int gq   = q0 + qi;
    const int d0   = quad * 16;

    const float* qp = base + (size_t)gq * QKV_N + d0;
    float4 q[4];
    #pragma unroll
    for (int i = 0; i < 4; ++i) q[i] = *reinterpret_cast<const float4*>(qp + i * 4);

    float s[9];
    #pragma unroll
    for (int j = 0; j < 9; ++j) {
        const float* kr = &Ks[qi + j][d0];
        float p = 0.f;
        #pragma unroll
        for (int i = 0; i < 4; ++i) {
            const float4 k4 = *reinterpret_cast<const float4*>(kr + i * 4);
            p += q[i].x * k4.x + q[i].y * k4.y + q[i].z * k4.z + q[i].w * k4.w;
        }
        p += __shfl_xor(p, 1);
        p += __shfl_xor(p, 2);
        const int gk = gq + j - RAD;
        s[j] = (gk >= 0 && gk < SS) ? p * 0.125f : -INFINITY;
    }
    float mx = s[0];
    #pragma unroll
    for (int j = 1; j < 9; ++j) mx = fmaxf(mx, s[j]);
    float pr[9]; float l = 0.f;
    #pragma unroll
    for (int j = 0; j < 9; ++j) { pr[j] = __expf(s[j] - mx); l += pr[j]; }
    const float inv = 1.0f / l;

    float o[16];
    #pragma unroll
    for (int i = 0; i < 16; ++i) o[i] = 0.f;
    #pragma unroll
    for (int j = 0; j < 9; ++j) {
        const float pj = pr[j] * inv;
        const float* vr = &Vs[qi + j][d0];
        #pragma unroll
        for (int i = 0; i < 16; i += 4) {
            const float4 v4 = *reinterpret_cast<const float4*>(vr + i);
            o[i]     = fmaf(pj, v4.x, o[i]);
            o[i + 1] = fmaf(pj, v4.y, o[i + 1]);
            o[i + 2] = fmaf(pj, v4.z, o[i + 2]);
            o[i + 3] = fmaf(pj, v4.w, o[i + 3]);
        }
    }
    const int col0 = h * DHH + d0;
    unsigned short* op = ctx + (size_t)(b * SS + gq) * 1024
                       + (size_t)(col0 >> 5) * 64 + (col0 & 31);
    us8 h0, h1, l0, l1;
    #pragma unroll
    for (int i = 0; i < 8; ++i) {
        h0[i] = f2bf(o[i]);      l0[i] = f2bf(o[i]     - bf2f(h0[i]));
        h1[i] = f2bf(o[8 + i]);  l1[i] = f2bf(o[8 + i] - bf2f(h1[i]));
    }
    *reinterpret_cast<us8*>(op)      = h0;
    *reinterpret_cast<us8*>(op + 8)  = h1;
    *reinterpret_cast<us8*>(op + 32) = l0;
    *reinterpret_cast<us8*>(op + 40) = l1;
}

// ---------------------------------------------------------------- launch
extern "C" void kernel_launch(void* const* d_in, const int* in_sizes, int n_in,
                              void* d_out, int out_size, void* d_ws, size_t ws_size,
                              hipStream_t stream)
{
    const float* x     = (const float*)d_in[0];
    const float* w_in  = (const float*)d_in[1];
    const float* b_in  = (const float*)d_in[2];
    const float* w_out = (const float*)d_in[3];
    const float* b_out = (const float*)d_in[4];
    const float* w_ff1 = (const float*)d_in[5];
    const float* b_ff1 = (const float*)d_in[6];
    const float* w_ff2 = (const float*)d_in[7];
    const float* b_ff2 = (const float*)d_in[8];
    const float* ln1_g = (const float*)d_in[9];
    const float* ln1_b = (const float*)d_in[10];
    const float* ln2_g = (const float*)d_in[11];
    const float* ln2_b = (const float*)d_in[12];
    float* out = (float*)d_out;

    char* ws = (char*)d_ws;
    unsigned short* lnq  = (unsigned short*)ws;
    float*          x1   = (float*)(ws + 16777216);
    unsigned short* ctxs = (unsigned short*)(ws + 2 * 16777216);
    float*          qkv  = (float*)(ws + 3 * 16777216);
    unsigned short* ffh  = (unsigned short*)(ws + 2 * 16777216);   // 67,108,864 B
    unsigned short* wqs  = (unsigned short*)(ws + 2 * 16777216 + 67108864);
    unsigned short* wos  = wqs + (size_t)1536 * 1024;
    unsigned short* w1s  = wos + (size_t)512 * 1024;
    unsigned short* w2s  = w1s + (size_t)2048 * 1024;

    conv_all<<<1536, 256, 0, stream>>>(w_in, w_out, w_ff1, w_ff2, wqs, w2s);

    // 1. LN1 -> split
    ln_kernel<<<MM, 128, 0, stream>>>(x, ln1_g, ln1_b, lnq);

    // 2. QKV (8-phase 256^2): grid 6x32 = 192
    gemm8<0><<<dim3(QKV_N / 256, MM / 256), 512, 0, stream>>>(
        lnq, wqs, b_in, qkv, nullptr, QKV_N, 512);

    // 3. local attention -> split ctx
    attn_kernel<<<dim3(SS / 64, BB, HH), 256, 0, stream>>>(qkv, ctxs);

    // 4. out-proj + residual (BN=64, 3 blocks/CU)
    gemm_tile<64, 1><<<dim3(DD / 64, MM / 128), 256, 0, stream>>>(
        ctxs, wos, b_out, x, x1, nullptr, DD, 512);

    // 5. LN2 -> split
    ln_kernel<<<MM, 128, 0, stream>>>(x1, ln2_g, ln2_b, lnq);

    // 6. FF1 + GELU (8-phase 256^2): grid 8x32 = 256, exact 1 block/CU
    gemm8<2><<<dim3(DFF / 256, MM / 256), 512, 0, stream>>>(
        lnq, w1s, b_ff1, nullptr, ffh, DFF, 512);

    // 7. FF2 + residual (BN=64, K=2048)
    gemm_tile<64, 1><<<dim3(DD / 64, MM / 128), 256, 0, stream>>>(
        ffh, w2s, b_ff2, x1, out, nullptr, DD, 2048);
}

// Round 13
// 127.792 us; speedup vs baseline: 1.6148x; 1.6148x over previous
//
#include <hip/hip_runtime.h>
#include <hip/hip_bf16.h>
#include <math.h>

// Problem constants
#define BB 4
#define SS 2048
#define DD 512
#define HH 8
#define DHH 64
#define DFF 2048
#define MM (BB*SS)          // 8192 rows
#define QKV_N (3*DD)        // 1536

typedef float  f32x4  __attribute__((ext_vector_type(4)));
typedef __bf16 bf16x8 __attribute__((ext_vector_type(8)));
typedef unsigned short us8 __attribute__((ext_vector_type(8)));
typedef unsigned short us4 __attribute__((ext_vector_type(4)));

// ---- bf16 helpers (RNE, finite inputs) ----
__device__ __forceinline__ unsigned short f2bf(float v) {
    unsigned int u = __float_as_uint(v);
    unsigned int r = (u + 0x7fffu + ((u >> 16) & 1u)) >> 16;
    return (unsigned short)r;
}
__device__ __forceinline__ float bf2f(unsigned short h) {
    return __uint_as_float(((unsigned int)h) << 16);
}

__device__ __forceinline__ f32x4 mfma_bf16(us8 a, us8 b, f32x4 c) {
    return __builtin_amdgcn_mfma_f32_16x16x32_bf16(
        __builtin_bit_cast(bf16x8, a), __builtin_bit_cast(bf16x8, b), c, 0, 0, 0);
}

// NOTE: imm offset of global_load_lds applies to BOTH global and LDS addresses
// (round-9 NaN post-mortem) — always pass 0 and advance pointers instead.
__device__ __forceinline__ void gload_lds16(const void* gsrc, void* ldst) {
    __builtin_amdgcn_global_load_lds(
        (const __attribute__((address_space(1))) void*)gsrc,
        (__attribute__((address_space(3))) void*)ldst, 16, 0, 0);
}

// Plain bf16 layout everywhere: row-major [R][K], 2B/elem.
// GEMM K-tile = 64 elems = 128 B/row, staged as 8 chunks of 16B with the
// row-XOR swizzle (slot = chunk ^ (row&7)). Fragment read for k-sub ks at
// chunk ks*4+kc; since (4+kc)^p = ((kc^p)^4), the ks=1 offset is ks0 ^ 32 ush.

// ---------------------------------------------------------------- LayerNorm -> bf16
__global__ __launch_bounds__(128)
void ln_kernel(const float* __restrict__ x, const float* __restrict__ g,
               const float* __restrict__ beta, unsigned short* __restrict__ outp)
{
    const int row = blockIdx.x;
    const int t = threadIdx.x;               // 128 threads, 4 floats each
    const float4 v = reinterpret_cast<const float4*>(x + (size_t)row * DD)[t];

    float s  = v.x + v.y + v.z + v.w;
    float s2 = v.x*v.x + v.y*v.y + v.z*v.z + v.w*v.w;
    #pragma unroll
    for (int off = 32; off >= 1; off >>= 1) {
        s  += __shfl_xor(s,  off);
        s2 += __shfl_xor(s2, off);
    }
    __shared__ float red[2][2];
    const int lane = t & 63, wid = t >> 6;
    if (lane == 0) { red[wid][0] = s; red[wid][1] = s2; }
    __syncthreads();
    const float ts  = red[0][0] + red[1][0];
    const float ts2 = red[0][1] + red[1][1];
    const float mu  = ts * (1.0f / DD);
    const float var = ts2 * (1.0f / DD) - mu * mu;
    const float rs  = rsqrtf(var + 1e-5f);

    const float4 gv = reinterpret_cast<const float4*>(g)[t];
    const float4 bv = reinterpret_cast<const float4*>(beta)[t];
    us4 hv;
    hv[0] = f2bf((v.x - mu) * rs * gv.x + bv.x);
    hv[1] = f2bf((v.y - mu) * rs * gv.y + bv.y);
    hv[2] = f2bf((v.z - mu) * rs * gv.z + bv.z);
    hv[3] = f2bf((v.w - mu) * rs * gv.w + bv.w);
    *reinterpret_cast<us4*>(outp + (size_t)row * DD + t * 4) = hv;
}

// ---------------------------------------------------------------- fp32 -> bf16 weights (one launch)
// units 0..262143: w_in|w_out|w_ff1 as 4096 rows x 512 K -> dst3 (plain bf16)
// units 262144..393215: w_ff2 512 rows x 2048 K -> dstw2
__global__ __launch_bounds__(256)
void conv_all(const float* __restrict__ w_in, const float* __restrict__ w_out,
              const float* __restrict__ w_ff1, const float* __restrict__ w_ff2,
              unsigned short* __restrict__ dst3, unsigned short* __restrict__ dstw2)
{
    const int gid = blockIdx.x * 256 + threadIdx.x;
    const float* src;
    unsigned short* dst;
    size_t o;
    if (gid < 262144) {
        const int r  = gid >> 6;
        const int k0 = (gid & 63) * 8;
        src = (r < 1536) ? w_in  + (size_t)r * 512 + k0
            : (r < 2048) ? w_out + (size_t)(r - 1536) * 512 + k0
                         : w_ff1 + (size_t)(r - 2048) * 512 + k0;
        o = (size_t)r * 512 + k0;
        dst = dst3;
    } else {
        const int g  = gid - 262144;
        const int r  = g >> 8;
        const int k0 = (g & 255) * 8;
        src = w_ff2 + (size_t)r * 2048 + k0;
        o = (size_t)r * 2048 + k0;
        dst = dstw2;
    }
    us8 h;
    #pragma unroll
    for (int i = 0; i < 8; ++i) h[i] = f2bf(src[i]);
    *reinterpret_cast<us8*>(dst + o) = h;
}

// ---------------------------------------------------------------- plain-bf16 MFMA GEMM
// BM=128, BN=64, BK=64: LDS 2 x (16KB A + 8KB B) = 48KB -> 3 blocks/CU (12 waves).
// 2-barrier double-buffered loop, x2-unrolled with static buffer indices.
// Per K-64 tile: 12 ds_read_b128 + 16 MFMA (2 k-subs x 4m x 2n).
// XCD-aware bijective block swizzle (requires nwg % 8 == 0).
// EPI: 0 = bias -> fp32 Cf; 1 = bias + Res -> fp32 Cf; 2 = bias + GELU -> bf16 Cs
template<int BN, int EPI>
__global__ __launch_bounds__(256, 3)
void gemm_tile(const unsigned short* __restrict__ Ax, const unsigned short* __restrict__ Wx,
               const float* __restrict__ bias, const float* __restrict__ Res,
               float* __restrict__ Cf, unsigned short* __restrict__ Cs,
               int N, int K)
{
    constexpr int NF   = BN / 32;          // n-frags per wave (2)
    constexpr int NB   = BN / 32;          // B stage loads per thread
    constexpr int AUSH = 128 * 64;         // ushorts per A buffer (16 KB)
    constexpr int BUSH = BN * 64;          // ushorts per B buffer (8 KB)
    __shared__ unsigned short smem[2][AUSH + BUSH];

    const int tid  = threadIdx.x;
    const int wave = tid >> 6, lane = tid & 63;
    const int wm = wave >> 1, wn = wave & 1;
    const int lr = lane & 15, kc = lane >> 4;

    // XCD swizzle: contiguous chunks of the flat grid per XCD
    const int nwg = gridDim.x * gridDim.y;
    int bid = blockIdx.y * gridDim.x + blockIdx.x;
    bid = (bid & 7) * (nwg >> 3) + (bid >> 3);
    const int bn = (bid % gridDim.x) * BN;
    const int bm = (bid / gridDim.x) * 128;

    const int nkb = K >> 6;                // K-64 tiles; even for all call sites (8 or 32)

    // LDS ush offsets of ks=0 fragments (ks=1 = ^32); chunk swizzled by row&7
    int aoff[4], woff[NF];
    #pragma unroll
    for (int m = 0; m < 4; ++m) {
        const int ra = wm * 64 + m * 16 + lr;
        aoff[m] = ra * 64 + ((kc ^ (ra & 7)) * 8);
    }
    #pragma unroll
    for (int n = 0; n < NF; ++n) {
        const int rw = wn * (NF * 16) + n * 16 + lr;
        woff[n] = AUSH + rw * 64 + ((kc ^ (rw & 7)) * 8);
    }

    f32x4 acc[4][NF];
    #pragma unroll
    for (int i = 0; i < 4; ++i)
        #pragma unroll
        for (int j = 0; j < NF; ++j) acc[i][j] = (f32x4){0.f, 0.f, 0.f, 0.f};

    // persistent staging pointers; source chunk = LDS slot ^ (row&7)
    const unsigned short* aP[4];
    const unsigned short* wP[NB];
    #pragma unroll
    for (int j = 0; j < 4; ++j) {
        const int off = j * 2048 + tid * 8;
        const int row = off >> 6;
        const int q   = ((off >> 3) & 7) ^ (row & 7);
        aP[j] = Ax + (size_t)(bm + row) * K + q * 8;
    }
    #pragma unroll
    for (int j = 0; j < NB; ++j) {
        const int off = j * 2048 + tid * 8;
        const int row = off >> 6;
        const int q   = ((off >> 3) & 7) ^ (row & 7);
        wP[j] = Wx + (size_t)(bn + row) * K + q * 8;
    }

#define STAGE_T(BUF) do {                                                      \
        _Pragma("unroll")                                                      \
        for (int j = 0; j < 4; ++j)                                            \
            gload_lds16(aP[j], &smem[BUF][j * 2048 + tid * 8]);                \
        _Pragma("unroll")                                                      \
        for (int j = 0; j < NB; ++j)                                           \
            gload_lds16(wP[j], &smem[BUF][AUSH + j * 2048 + tid * 8]);         \
    } while (0)

#define ADV_T() do {                                                           \
        _Pragma("unroll")                                                      \
        for (int j = 0; j < 4; ++j) aP[j] += 64;                               \
        _Pragma("unroll")                                                      \
        for (int j = 0; j < NB; ++j) wP[j] += 64;                              \
    } while (0)

// one K-64 tile: ks=0 frags at aoff/woff, ks=1 at ^32
#define COMPUTE_T(BUF) do {                                                    \
        const unsigned short* S = smem[BUF];                                   \
        us8 a0[4], a1[4], w0[NF], w1[NF];                                      \
        _Pragma("unroll")                                                      \
        for (int m = 0; m < 4; ++m) {                                          \
            a0[m] = *reinterpret_cast<const us8*>(S + aoff[m]);                \
            a1[m] = *reinterpret_cast<const us8*>(S + (aoff[m] ^ 32));         \
        }                                                                      \
        _Pragma("unroll")                                                      \
        for (int n = 0; n < NF; ++n) {                                         \
            w0[n] = *reinterpret_cast<const us8*>(S + woff[n]);                \
            w1[n] = *reinterpret_cast<const us8*>(S + (woff[n] ^ 32));         \
        }                                                                      \
        _Pragma("unroll")                                                      \
        for (int m = 0; m < 4; ++m)                                            \
            _Pragma("unroll")                                                  \
            for (int n = 0; n < NF; ++n) {                                     \
                acc[m][n] = mfma_bf16(a0[m], w0[n], acc[m][n]);                \
                acc[m][n] = mfma_bf16(a1[m], w1[n], acc[m][n]);                \
            }                                                                  \
    } while (0)

    STAGE_T(0); ADV_T();
    for (int kb = 0; kb < nkb; kb += 2) {
        __syncthreads();                            // buf0 arrived; prev buf1 readers done
        STAGE_T(1); ADV_T();                        // tile kb+1 -> buf1
        COMPUTE_T(0);                               // tile kb
        __syncthreads();                            // buf1 arrived; buf0 readers done
        if (kb + 2 < nkb) STAGE_T(0);               // tile kb+2 -> buf0
        ADV_T();
        COMPUTE_T(1);                               // tile kb+1
    }
#undef STAGE_T
#undef ADV_T
#undef COMPUTE_T

    // epilogue; C/D layout: col = lane&15, row = (lane>>4)*4 + reg
    float bvn[NF];
    #pragma unroll
    for (int n = 0; n < NF; ++n) bvn[n] = bias[bn + wn * (NF * 16) + n * 16 + lr];

    #pragma unroll
    for (int m = 0; m < 4; ++m) {
        #pragma unroll
        for (int j = 0; j < 4; ++j) {
            const int row = bm + wm * 64 + m * 16 + kc * 4 + j;
            #pragma unroll
            for (int n = 0; n < NF; ++n) {
                const int col = bn + wn * (NF * 16) + n * 16 + lr;
                float v = acc[m][n][j] + bvn[n];
                if constexpr (EPI == 1) v += Res[(size_t)row * N + col];
                if constexpr (EPI == 2) {
                    v = 0.5f * v * (1.0f + erff(v * 0.70710678118654752f));
                    Cs[(size_t)row * N + col] = f2bf(v);
                } else {
                    Cf[(size_t)row * N + col] = v;
                }
            }
        }
    }
}

// ---------------------------------------------------------------- Local attention (fp32 in, bf16 out)
__global__ __launch_bounds__(256)
void attn_kernel(const float* __restrict__ qkv, unsigned short* __restrict__ ctx)
{
    constexpr int RAD = 4;
    constexpr int TQ  = 64;
    constexpr int KROWS = TQ + 2 * RAD;   // 72
    constexpr int LDK = DHH + 4;          // 68

    __shared__ float Ks[KROWS][LDK];
    __shared__ float Vs[KROWS][LDK];

    const int t  = threadIdx.x;
    const int qt = blockIdx.x;
    const int b  = blockIdx.y;
    const int h  = blockIdx.z;
    const int q0 = qt * TQ;
    const float* base = qkv + ((size_t)b * SS) * QKV_N + h * DHH;

    for (int idx = t; idx < KROWS * (DHH / 4); idx += 256) {
        const int row = idx >> 4;
        const int c4  = idx & 15;
        const int gr  = q0 - RAD + row;
        float4 kv = make_float4(0.f, 0.f, 0.f, 0.f);
        float4 vv = kv;
        if (gr >= 0 && gr < SS) {
            const float* p = base + (size_t)gr * QKV_N;
            kv = *reinterpret_cast<const float4*>(p + DD     + c4 * 4);
            vv = *reinterpret_cast<const float4*>(p + 2 * DD + c4 * 4);
        }
        *reinterpret_cast<float4*>(&Ks[row][c4 * 4]) = kv;
        *reinterpret_cast<float4*>(&Vs[row][c4 * 4]) = vv;
    }
    __syncthreads();

    const int qi   = t >> 2;
    const int quad = t & 3;
    const int gq   = q0 + qi;
    const int d0   = quad * 16;

    const float* qp = base + (size_t)gq * QKV_N + d0;
    float4 q[4];
    #pragma unroll
    for (int i = 0; i < 4; ++i) q[i] = *reinterpret_cast<const float4*>(qp + i * 4);

    float s[9];
    #pragma unroll
    for (int j = 0; j < 9; ++j) {
        const float* kr = &Ks[qi + j][d0];
        float p = 0.f;
        #pragma unroll
        for (int i = 0; i < 4; ++i) {
            const float4 k4 = *reinterpret_cast<const float4*>(kr + i * 4);
            p += q[i].x * k4.x + q[i].y * k4.y + q[i].z * k4.z + q[i].w * k4.w;
        }
        p += __shfl_xor(p, 1);
        p += __shfl_xor(p, 2);
        const int gk = gq + j - RAD;
        s[j] = (gk >= 0 && gk < SS) ? p * 0.125f : -INFINITY;
    }
    float mx = s[0];
    #pragma unroll
    for (int j = 1; j < 9; ++j) mx = fmaxf(mx, s[j]);
    float pr[9]; float l = 0.f;
    #pragma unroll
    for (int j = 0; j < 9; ++j) { pr[j] = __expf(s[j] - mx); l += pr[j]; }
    const float inv = 1.0f / l;

    float o[16];
    #pragma unroll
    for (int i = 0; i < 16; ++i) o[i] = 0.f;
    #pragma unroll
    for (int j = 0; j < 9; ++j) {
        const float pj = pr[j] * inv;
        const float* vr = &Vs[qi + j][d0];
        #pragma unroll
        for (int i = 0; i < 16; i += 4) {
            const float4 v4 = *reinterpret_cast<const float4*>(vr + i);
            o[i]     = fmaf(pj, v4.x, o[i]);
            o[i + 1] = fmaf(pj, v4.y, o[i + 1]);
            o[i + 2] = fmaf(pj, v4.z, o[i + 2]);
            o[i + 3] = fmaf(pj, v4.w, o[i + 3]);
        }
    }
    // write plain-bf16 ctx: row = b*SS+gq, cols col0..col0+15
    unsigned short* op = ctx + (size_t)(b * SS + gq) * DD + h * DHH + d0;
    us8 h0, h1;
    #pragma unroll
    for (int i = 0; i < 8; ++i) {
        h0[i] = f2bf(o[i]);
        h1[i] = f2bf(o[8 + i]);
    }
    *reinterpret_cast<us8*>(op)     = h0;
    *reinterpret_cast<us8*>(op + 8) = h1;
}

// ---------------------------------------------------------------- launch
extern "C" void kernel_launch(void* const* d_in, const int* in_sizes, int n_in,
                              void* d_out, int out_size, void* d_ws, size_t ws_size,
                              hipStream_t stream)
{
    const float* x     = (const float*)d_in[0];
    const float* w_in  = (const float*)d_in[1];
    const float* b_in  = (const float*)d_in[2];
    const float* w_out = (const float*)d_in[3];
    const float* b_out = (const float*)d_in[4];
    const float* w_ff1 = (const float*)d_in[5];
    const float* b_ff1 = (const float*)d_in[6];
    const float* w_ff2 = (const float*)d_in[7];
    const float* b_ff2 = (const float*)d_in[8];
    const float* ln1_g = (const float*)d_in[9];
    const float* ln1_b = (const float*)d_in[10];
    const float* ln2_g = (const float*)d_in[11];
    const float* ln2_b = (const float*)d_in[12];
    float* out = (float*)d_out;

    // workspace layout (bytes):
    // [0,16M)    lnq   bf16 [8192][512]  (8 MB used; LN1 out, reused for LN2)
    // [16M,32M)  x1    fp32 [8192][512]
    // [32M,48M)  ctxs  bf16 [8192][512]  (8 MB; dead before ffh is written)
    // [32M,64M)  ffh   bf16 [8192][2048] (32 MB; written step 6 over dead ctxs/qkv space)
    // [48M,98.3M) qkv  fp32 [8192][1536] (dead after step 3)
    // [99.1M..]  weights bf16 (wqs|wos|w1s contiguous, then w2s)
    char* ws = (char*)d_ws;
    unsigned short* lnq  = (unsigned short*)ws;
    float*          x1   = (float*)(ws + 16777216);
    unsigned short* ctxs = (unsigned short*)(ws + 2 * 16777216);
    float*          qkv  = (float*)(ws + 3 * 16777216);
    unsigned short* ffh  = (unsigned short*)(ws + 2 * 16777216);
    unsigned short* wqs  = (unsigned short*)(ws + 2 * 16777216 + 67108864);
    unsigned short* wos  = wqs + (size_t)1536 * 512;
    unsigned short* w1s  = wos + (size_t)512 * 512;
    unsigned short* w2s  = w1s + (size_t)2048 * 512;

    // weight conversions: one launch for all four weights
    conv_all<<<1536, 256, 0, stream>>>(w_in, w_out, w_ff1, w_ff2, wqs, w2s);

    // 1. LN1 -> bf16
    ln_kernel<<<MM, 128, 0, stream>>>(x, ln1_g, ln1_b, lnq);

    // 2. QKV: [8192,512]x[1536,512]^T -> fp32 qkv   (BN=64: grid 1536, 3 blocks/CU)
    gemm_tile<64, 0><<<dim3(QKV_N / 64, MM / 128), 256, 0, stream>>>(
        lnq, wqs, b_in, nullptr, qkv, nullptr, QKV_N, 512);

    // 3. local attention -> bf16 ctx
    attn_kernel<<<dim3(SS / 64, BB, HH), 256, 0, stream>>>(qkv, ctxs);

    // 4. out-proj + residual: x1 = x + ctx @ out_w^T + b
    gemm_tile<64, 1><<<dim3(DD / 64, MM / 128), 256, 0, stream>>>(
        ctxs, wos, b_out, x, x1, nullptr, DD, 512);

    // 5. LN2 -> bf16
    ln_kernel<<<MM, 128, 0, stream>>>(x1, ln2_g, ln2_b, lnq);

    // 6. FF1 + GELU -> bf16 ffh
    gemm_tile<64, 2><<<dim3(DFF / 64, MM / 128), 256, 0, stream>>>(
        lnq, w1s, b_ff1, nullptr, nullptr, ffh, DFF, 512);

    // 7. FF2 + residual: out = x1 + ffh @ ff_w2^T + b   (K=2048)
    gemm_tile<64, 1><<<dim3(DD / 64, MM / 128), 256, 0, stream>>>(
        ffh, w2s, b_ff2, x1, out, nullptr, DD, 2048);
}

// Round 16
// 122.364 us; speedup vs baseline: 1.6865x; 1.0444x over previous
//
#include <hip/hip_runtime.h>
#include <hip/hip_bf16.h>
#include <math.h>

// Problem constants
#define BB 4
#define SS 2048
#define DD 512
#define HH 8
#define DHH 64
#define DFF 2048
#define MM (BB*SS)          // 8192 rows
#define QKV_N (3*DD)        // 1536

typedef float  f32x4  __attribute__((ext_vector_type(4)));
typedef __bf16 bf16x8 __attribute__((ext_vector_type(8)));
typedef unsigned short us8 __attribute__((ext_vector_type(8)));
typedef unsigned short us4 __attribute__((ext_vector_type(4)));

// ---- bf16 helpers (RNE, finite inputs) ----
__device__ __forceinline__ unsigned short f2bf(float v) {
    unsigned int u = __float_as_uint(v);
    unsigned int r = (u + 0x7fffu + ((u >> 16) & 1u)) >> 16;
    return (unsigned short)r;
}
__device__ __forceinline__ float bf2f(unsigned short h) {
    return __uint_as_float(((unsigned int)h) << 16);
}

__device__ __forceinline__ f32x4 mfma_bf16(us8 a, us8 b, f32x4 c) {
    return __builtin_amdgcn_mfma_f32_16x16x32_bf16(
        __builtin_bit_cast(bf16x8, a), __builtin_bit_cast(bf16x8, b), c, 0, 0, 0);
}

// NOTE: imm offset of global_load_lds applies to BOTH global and LDS addresses
// (round-9 NaN post-mortem) — always pass 0 and advance pointers instead.
__device__ __forceinline__ void gload_lds16(const void* gsrc, void* ldst) {
    __builtin_amdgcn_global_load_lds(
        (const __attribute__((address_space(1))) void*)gsrc,
        (__attribute__((address_space(3))) void*)ldst, 16, 0, 0);
}

// ---------------------------------------------------------------- LayerNorm -> bf16
__global__ __launch_bounds__(128)
void ln_kernel(const float* __restrict__ x, const float* __restrict__ g,
               const float* __restrict__ beta, unsigned short* __restrict__ outp)
{
    const int row = blockIdx.x;
    const int t = threadIdx.x;               // 128 threads, 4 floats each
    const float4 v = reinterpret_cast<const float4*>(x + (size_t)row * DD)[t];

    float s  = v.x + v.y + v.z + v.w;
    float s2 = v.x*v.x + v.y*v.y + v.z*v.z + v.w*v.w;
    #pragma unroll
    for (int off = 32; off >= 1; off >>= 1) {
        s  += __shfl_xor(s,  off);
        s2 += __shfl_xor(s2, off);
    }
    __shared__ float red[2][2];
    const int lane = t & 63, wid = t >> 6;
    if (lane == 0) { red[wid][0] = s; red[wid][1] = s2; }
    __syncthreads();
    const float ts  = red[0][0] + red[1][0];
    const float ts2 = red[0][1] + red[1][1];
    const float mu  = ts * (1.0f / DD);
    const float var = ts2 * (1.0f / DD) - mu * mu;
    const float rs  = rsqrtf(var + 1e-5f);

    const float4 gv = reinterpret_cast<const float4*>(g)[t];
    const float4 bv = reinterpret_cast<const float4*>(beta)[t];
    us4 hv;
    hv[0] = f2bf((v.x - mu) * rs * gv.x + bv.x);
    hv[1] = f2bf((v.y - mu) * rs * gv.y + bv.y);
    hv[2] = f2bf((v.z - mu) * rs * gv.z + bv.z);
    hv[3] = f2bf((v.w - mu) * rs * gv.w + bv.w);
    *reinterpret_cast<us4*>(outp + (size_t)row * DD + t * 4) = hv;
}

// ---------------------------------------------------------------- fp32 -> bf16 weights (one launch)
__global__ __launch_bounds__(256)
void conv_all(const float* __restrict__ w_in, const float* __restrict__ w_out,
              const float* __restrict__ w_ff1, const float* __restrict__ w_ff2,
              unsigned short* __restrict__ dst3, unsigned short* __restrict__ dstw2)
{
    const int gid = blockIdx.x * 256 + threadIdx.x;
    const float* src;
    unsigned short* dst;
    size_t o;
    if (gid < 262144) {
        const int r  = gid >> 6;
        const int k0 = (gid & 63) * 8;
        src = (r < 1536) ? w_in  + (size_t)r * 512 + k0
            : (r < 2048) ? w_out + (size_t)(r - 1536) * 512 + k0
                         : w_ff1 + (size_t)(r - 2048) * 512 + k0;
        o = (size_t)r * 512 + k0;
        dst = dst3;
    } else {
        const int g  = gid - 262144;
        const int r  = g >> 8;
        const int k0 = (g & 255) * 8;
        src = w_ff2 + (size_t)r * 2048 + k0;
        o = (size_t)r * 2048 + k0;
        dst = dstw2;
    }
    us8 h;
    #pragma unroll
    for (int i = 0; i < 8; ++i) h[i] = f2bf(src[i]);
    *reinterpret_cast<us8*>(dst + o) = h;
}

// ---------------------------------------------------------------- BK=32 BN=128 bf16 GEMM (QKV, FF1)
// BM=128, BN=128, BK=32: LDS 2 x (8KB A + 8KB B) = 32KB -> 4 blocks/CU (16 waves).
// K-tile = 32 elems = 64B/row = 4 chunks of 16B; swizzle slot = chunk ^ (row&3)
// (bank-balanced: wave's b128 reads spread evenly, 8 cy/KB = LDS floor).
// Per tile: 8 ds_read_b128 + 16 MFMA (4m x 4n); 4 stage loads/thread.
// EPI: 2 = bias + GELU -> bf16 Cs; 3 = bias -> bf16 Cs
template<int EPI>
__global__ __launch_bounds__(256, 4)
void gemm_k32(const unsigned short* __restrict__ Ax, const unsigned short* __restrict__ Wx,
              const float* __restrict__ bias, unsigned short* __restrict__ Cs,
              int N, int K)
{
    constexpr int AUSH = 128 * 32;         // 4096 ush = 8 KB
    __shared__ unsigned short smem[2][2 * AUSH];

    const int tid  = threadIdx.x;
    const int wave = tid >> 6, lane = tid & 63;
    const int wm = wave >> 1, wn = wave & 1;
    const int lr = lane & 15, kc = lane >> 4;

    const int nwg = gridDim.x * gridDim.y;
    int bid = blockIdx.y * gridDim.x + blockIdx.x;
    bid = (bid & 7) * (nwg >> 3) + (bid >> 3);
    const int bn = (bid % gridDim.x) * 128;
    const int bm = (bid / gridDim.x) * 128;

    const int nkb = K >> 5;                // 16 for K=512 (even)

    int aoff[4], woff[4];
    #pragma unroll
    for (int m = 0; m < 4; ++m) {
        const int ra = wm * 64 + m * 16 + lr;
        aoff[m] = ra * 32 + ((kc ^ (ra & 3)) * 8);
    }
    #pragma unroll
    for (int n = 0; n < 4; ++n) {
        const int rw = wn * 64 + n * 16 + lr;
        woff[n] = AUSH + rw * 32 + ((kc ^ (rw & 3)) * 8);
    }

    f32x4 acc[4][4];
    #pragma unroll
    for (int i = 0; i < 4; ++i)
        #pragma unroll
        for (int j = 0; j < 4; ++j) acc[i][j] = (f32x4){0.f, 0.f, 0.f, 0.f};

    // staging pointers: load j covers LDS off = j*2048 + tid*8 (ush)
    const unsigned short* aP[2];
    const unsigned short* wP[2];
    #pragma unroll
    for (int j = 0; j < 2; ++j) {
        const int off = j * 2048 + tid * 8;
        const int row = off >> 5;
        const int q   = ((off >> 3) & 3) ^ (row & 3);
        aP[j] = Ax + (size_t)(bm + row) * K + q * 8;
        wP[j] = Wx + (size_t)(bn + row) * K + q * 8;
    }

#define STAGE_T(BUF) do {                                                      \
        _Pragma("unroll")                                                      \
        for (int j = 0; j < 2; ++j) {                                          \
            gload_lds16(aP[j], &smem[BUF][j * 2048 + tid * 8]);                \
            gload_lds16(wP[j], &smem[BUF][AUSH + j * 2048 + tid * 8]);         \
        }                                                                      \
    } while (0)

#define ADV_T() do {                                                           \
        _Pragma("unroll")                                                      \
        for (int j = 0; j < 2; ++j) { aP[j] += 32; wP[j] += 32; }              \
    } while (0)

#define COMPUTE_T(BUF) do {                                                    \
        const unsigned short* S = smem[BUF];                                   \
        us8 a[4], w[4];                                                        \
        _Pragma("unroll")                                                      \
        for (int m = 0; m < 4; ++m)                                            \
            a[m] = *reinterpret_cast<const us8*>(S + aoff[m]);                 \
        _Pragma("unroll")                                                      \
        for (int n = 0; n < 4; ++n)                                            \
            w[n] = *reinterpret_cast<const us8*>(S + woff[n]);                 \
        _Pragma("unroll")                                                      \
        for (int m = 0; m < 4; ++m)                                            \
            _Pragma("unroll")                                                  \
            for (int n = 0; n < 4; ++n)                                        \
                acc[m][n] = mfma_bf16(a[m], w[n], acc[m][n]);                  \
    } while (0)

    STAGE_T(0); ADV_T();
    for (int kb = 0; kb < nkb; kb += 2) {
        __syncthreads();
        STAGE_T(1); ADV_T();
        COMPUTE_T(0);
        __syncthreads();
        if (kb + 2 < nkb) STAGE_T(0);
        ADV_T();
        COMPUTE_T(1);
    }
#undef STAGE_T
#undef ADV_T
#undef COMPUTE_T

    // epilogue; C/D layout: col = lane&15, row = (lane>>4)*4 + reg
    float bvn[4];
    #pragma unroll
    for (int n = 0; n < 4; ++n) bvn[n] = bias[bn + wn * 64 + n * 16 + lr];

    #pragma unroll
    for (int m = 0; m < 4; ++m) {
        #pragma unroll
        for (int j = 0; j < 4; ++j) {
            const int row = bm + wm * 64 + m * 16 + kc * 4 + j;
            #pragma unroll
            for (int n = 0; n < 4; ++n) {
                const int col = bn + wn * 64 + n * 16 + lr;
                float v = acc[m][n][j] + bvn[n];
                if constexpr (EPI == 2)
                    v = 0.5f * v * (1.0f + erff(v * 0.70710678118654752f));
                Cs[(size_t)row * N + col] = f2bf(v);
            }
        }
    }
}

// ---------------------------------------------------------------- BN=64 BK=64 bf16 GEMM (oproj, FF2)
// Proven round-13 kernel: 48KB LDS -> 3 blocks/CU, 2-barrier dbuf, x2-unrolled.
// EPI: 1 = bias + Res -> fp32 Cf
template<int BN, int EPI>
__global__ __launch_bounds__(256, 3)
void gemm_tile(const unsigned short* __restrict__ Ax, const unsigned short* __restrict__ Wx,
               const float* __restrict__ bias, const float* __restrict__ Res,
               float* __restrict__ Cf, unsigned short* __restrict__ Cs,
               int N, int K)
{
    constexpr int NF   = BN / 32;
    constexpr int NB   = BN / 32;
    constexpr int AUSH = 128 * 64;
    constexpr int BUSH = BN * 64;
    __shared__ unsigned short smem[2][AUSH + BUSH];

    const int tid  = threadIdx.x;
    const int wave = tid >> 6, lane = tid & 63;
    const int wm = wave >> 1, wn = wave & 1;
    const int lr = lane & 15, kc = lane >> 4;

    const int nwg = gridDim.x * gridDim.y;
    int bid = blockIdx.y * gridDim.x + blockIdx.x;
    bid = (bid & 7) * (nwg >> 3) + (bid >> 3);
    const int bn = (bid % gridDim.x) * BN;
    const int bm = (bid / gridDim.x) * 128;

    const int nkb = K >> 6;

    int aoff[4], woff[NF];
    #pragma unroll
    for (int m = 0; m < 4; ++m) {
        const int ra = wm * 64 + m * 16 + lr;
        aoff[m] = ra * 64 + ((kc ^ (ra & 7)) * 8);
    }
    #pragma unroll
    for (int n = 0; n < NF; ++n) {
        const int rw = wn * (NF * 16) + n * 16 + lr;
        woff[n] = AUSH + rw * 64 + ((kc ^ (rw & 7)) * 8);
    }

    f32x4 acc[4][NF];
    #pragma unroll
    for (int i = 0; i < 4; ++i)
        #pragma unroll
        for (int j = 0; j < NF; ++j) acc[i][j] = (f32x4){0.f, 0.f, 0.f, 0.f};

    const unsigned short* aP[4];
    const unsigned short* wP[NB];
    #pragma unroll
    for (int j = 0; j < 4; ++j) {
        const int off = j * 2048 + tid * 8;
        const int row = off >> 6;
        const int q   = ((off >> 3) & 7) ^ (row & 7);
        aP[j] = Ax + (size_t)(bm + row) * K + q * 8;
    }
    #pragma unroll
    for (int j = 0; j < NB; ++j) {
        const int off = j * 2048 + tid * 8;
        const int row = off >> 6;
        const int q   = ((off >> 3) & 7) ^ (row & 7);
        wP[j] = Wx + (size_t)(bn + row) * K + q * 8;
    }

#define STAGE_T(BUF) do {                                                      \
        _Pragma("unroll")                                                      \
        for (int j = 0; j < 4; ++j)                                            \
            gload_lds16(aP[j], &smem[BUF][j * 2048 + tid * 8]);                \
        _Pragma("unroll")                                                      \
        for (int j = 0; j < NB; ++j)                                           \
            gload_lds16(wP[j], &smem[BUF][AUSH + j * 2048 + tid * 8]);         \
    } while (0)

#define ADV_T() do {                                                           \
        _Pragma("unroll")                                                      \
        for (int j = 0; j < 4; ++j) aP[j] += 64;                               \
        _Pragma("unroll")                                                      \
        for (int j = 0; j < NB; ++j) wP[j] += 64;                              \
    } while (0)

#define COMPUTE_T(BUF) do {                                                    \
        const unsigned short* S = smem[BUF];                                   \
        us8 a0[4], a1[4], w0[NF], w1[NF];                                      \
        _Pragma("unroll")                                                      \
        for (int m = 0; m < 4; ++m) {                                          \
            a0[m] = *reinterpret_cast<const us8*>(S + aoff[m]);                \
            a1[m] = *reinterpret_cast<const us8*>(S + (aoff[m] ^ 32));         \
        }                                                                      \
        _Pragma("unroll")                                                      \
        for (int n = 0; n < NF; ++n) {                                         \
            w0[n] = *reinterpret_cast<const us8*>(S + woff[n]);                \
            w1[n] = *reinterpret_cast<const us8*>(S + (woff[n] ^ 32));         \
        }                                                                      \
        _Pragma("unroll")                                                      \
        for (int m = 0; m < 4; ++m)                                            \
            _Pragma("unroll")                                                  \
            for (int n = 0; n < NF; ++n) {                                     \
                acc[m][n] = mfma_bf16(a0[m], w0[n], acc[m][n]);                \
                acc[m][n] = mfma_bf16(a1[m], w1[n], acc[m][n]);                \
            }                                                                  \
    } while (0)

    STAGE_T(0); ADV_T();
    for (int kb = 0; kb < nkb; kb += 2) {
        __syncthreads();
        STAGE_T(1); ADV_T();
        COMPUTE_T(0);
        __syncthreads();
        if (kb + 2 < nkb) STAGE_T(0);
        ADV_T();
        COMPUTE_T(1);
    }
#undef STAGE_T
#undef ADV_T
#undef COMPUTE_T

    float bvn[NF];
    #pragma unroll
    for (int n = 0; n < NF; ++n) bvn[n] = bias[bn + wn * (NF * 16) + n * 16 + lr];

    #pragma unroll
    for (int m = 0; m < 4; ++m) {
        #pragma unroll
        for (int j = 0; j < 4; ++j) {
            const int row = bm + wm * 64 + m * 16 + kc * 4 + j;
            #pragma unroll
            for (int n = 0; n < NF; ++n) {
                const int col = bn + wn * (NF * 16) + n * 16 + lr;
                float v = acc[m][n][j] + bvn[n];
                if constexpr (EPI == 1) v += Res[(size_t)row * N + col];
                if constexpr (EPI == 2) {
                    v = 0.5f * v * (1.0f + erff(v * 0.70710678118654752f));
                    Cs[(size_t)row * N + col] = f2bf(v);
                } else {
                    Cf[(size_t)row * N + col] = v;
                }
            }
        }
    }
}

// ---------------------------------------------------------------- Local attention (bf16 qkv in, bf16 out)
__global__ __launch_bounds__(256)
void attn_kernel(const unsigned short* __restrict__ qkv, unsigned short* __restrict__ ctx)
{
    constexpr int RAD = 4;
    constexpr int TQ  = 64;
    constexpr int KROWS = TQ + 2 * RAD;   // 72
    constexpr int LDK = DHH + 4;          // 68

    __shared__ float Ks[KROWS][LDK];
    __shared__ float Vs[KROWS][LDK];

    const int t  = threadIdx.x;
    const int qt = blockIdx.x;
    const int b  = blockIdx.y;
    const int h  = blockIdx.z;
    const int q0 = qt * TQ;
    const unsigned short* base = qkv + (size_t)(b * SS) * QKV_N + h * DHH;

    for (int idx = t; idx < KROWS * 8; idx += 256) {
        const int row = idx >> 3;
        const int c8  = idx & 7;              // 8 elems per unit
        const int gr  = q0 - RAD + row;
        float kf[8], vf[8];
        if (gr >= 0 && gr < SS) {
            const unsigned short* p = base + (size_t)gr * QKV_N;
            const us8 kv = *reinterpret_cast<const us8*>(p + DD     + c8 * 8);
            const us8 vv = *reinterpret_cast<const us8*>(p + 2 * DD + c8 * 8);
            #pragma unroll
            for (int i = 0; i < 8; ++i) { kf[i] = bf2f(kv[i]); vf[i] = bf2f(vv[i]); }
        } else {
            #pragma unroll
            for (int i = 0; i < 8; ++i) { kf[i] = 0.f; vf[i] = 0.f; }
        }
        #pragma unroll
        for (int i = 0; i < 8; i += 4) {
            *reinterpret_cast<float4*>(&Ks[row][c8 * 8 + i]) =
                make_float4(kf[i], kf[i+1], kf[i+2], kf[i+3]);
            *reinterpret_cast<float4*>(&Vs[row][c8 * 8 + i]) =
                make_float4(vf[i], vf[i+1], vf[i+2], vf[i+3]);
        }
    }
    __syncthreads();

    const int qi   = t >> 2;
    const int quad = t & 3;
    const int gq   = q0 + qi;
    const int d0   = quad * 16;

    const unsigned short* qp = base + (size_t)gq * QKV_N + d0;
    float q[16];
    {
        const us8 qa = *reinterpret_cast<const us8*>(qp);
        const us8 qb = *reinterpret_cast<const us8*>(qp + 8);
        #pragma unroll
        for (int i = 0; i < 8; ++i) { q[i] = bf2f(qa[i]); q[8 + i] = bf2f(qb[i]); }
    }

    float s[9];
    #pragma unroll
    for (int j = 0; j < 9; ++j) {
        const float* kr = &Ks[qi + j][d0];
        float p = 0.f;
        #pragma unroll
        for (int i = 0; i < 16; i += 4) {
            const float4 k4 = *reinterpret_cast<const float4*>(kr + i);
            p += q[i] * k4.x + q[i+1] * k4.y + q[i+2] * k4.z + q[i+3] * k4.w;
        }
        p += __shfl_xor(p, 1);
        p += __shfl_xor(p, 2);
        const int gk = gq + j - RAD;
        s[j] = (gk >= 0 && gk < SS) ? p * 0.125f : -INFINITY;
    }
    float mx = s[0];
    #pragma unroll
    for (int j = 1; j < 9; ++j) mx = fmaxf(mx, s[j]);
    float pr[9]; float l = 0.f;
    #pragma unroll
    for (int j = 0; j < 9; ++j) { pr[j] = __expf(s[j] - mx); l += pr[j]; }
    const float inv = 1.0f / l;

    float o[16];
    #pragma unroll
    for (int i = 0; i < 16; ++i) o[i] = 0.f;
    #pragma unroll
    for (int j = 0; j < 9; ++j) {
        const float pj = pr[j] * inv;
        const float* vr = &Vs[qi + j][d0];
        #pragma unroll
        for (int i = 0; i < 16; i += 4) {
            const float4 v4 = *reinterpret_cast<const float4*>(vr + i);
            o[i]     = fmaf(pj, v4.x, o[i]);
            o[i + 1] = fmaf(pj, v4.y, o[i + 1]);
            o[i + 2] = fmaf(pj, v4.z, o[i + 2]);
            o[i + 3] = fmaf(pj, v4.w, o[i + 3]);
        }
    }
    unsigned short* op = ctx + (size_t)(b * SS + gq) * DD + h * DHH + d0;
    us8 h0, h1;
    #pragma unroll
    for (int i = 0; i < 8; ++i) {
        h0[i] = f2bf(o[i]);
        h1[i] = f2bf(o[8 + i]);
    }
    *reinterpret_cast<us8*>(op)     = h0;
    *reinterpret_cast<us8*>(op + 8) = h1;
}

// ---------------------------------------------------------------- launch
extern "C" void kernel_launch(void* const* d_in, const int* in_sizes, int n_in,
                              void* d_out, int out_size, void* d_ws, size_t ws_size,
                              hipStream_t stream)
{
    const float* x     = (const float*)d_in[0];
    const float* w_in  = (const float*)d_in[1];
    const float* b_in  = (const float*)d_in[2];
    const float* w_out = (const float*)d_in[3];
    const float* b_out = (const float*)d_in[4];
    const float* w_ff1 = (const float*)d_in[5];
    const float* b_ff1 = (const float*)d_in[6];
    const float* w_ff2 = (const float*)d_in[7];
    const float* b_ff2 = (const float*)d_in[8];
    const float* ln1_g = (const float*)d_in[9];
    const float* ln1_b = (const float*)d_in[10];
    const float* ln2_g = (const float*)d_in[11];
    const float* ln2_b = (const float*)d_in[12];
    float* out = (float*)d_out;

    // workspace layout (bytes):
    // [0,16M)    lnq   bf16 [8192][512]   (LN out, reused for LN2)
    // [16M,32M)  x1    fp32 [8192][512]
    // [32M,48M)  ctxs  bf16 [8192][512]   (dead before ffh written)
    // [32M,64M)  ffh   bf16 [8192][2048]  (step 6, over dead ctxs/qkv)
    // [48M,72M)  qkv   bf16 [8192][1536]  (dead after step 3)
    // [99.1M..]  weights bf16 (wqs|wos|w1s contiguous, then w2s)
    char* ws = (char*)d_ws;
    unsigned short* lnq  = (unsigned short*)ws;
    float*          x1   = (float*)(ws + 16777216);
    unsigned short* ctxs = (unsigned short*)(ws + 2 * 16777216);
    unsigned short* qkv  = (unsigned short*)(ws + 3 * 16777216);
    unsigned short* ffh  = (unsigned short*)(ws + 2 * 16777216);
    unsigned short* wqs  = (unsigned short*)(ws + 2 * 16777216 + 67108864);
    unsigned short* wos  = wqs + (size_t)1536 * 512;
    unsigned short* w1s  = wos + (size_t)512 * 512;
    unsigned short* w2s  = w1s + (size_t)2048 * 512;

    // weight conversions: one launch for all four weights
    conv_all<<<1536, 256, 0, stream>>>(w_in, w_out, w_ff1, w_ff2, wqs, w2s);

    // 1. LN1 -> bf16
    ln_kernel<<<MM, 128, 0, stream>>>(x, ln1_g, ln1_b, lnq);

    // 2. QKV -> bf16 qkv   (BK=32 BN=128: grid 768, 4 blocks/CU)
    gemm_k32<3><<<dim3(QKV_N / 128, MM / 128), 256, 0, stream>>>(
        lnq, wqs, b_in, qkv, QKV_N, 512);

    // 3. local attention -> bf16 ctx
    attn_kernel<<<dim3(SS / 64, BB, HH), 256, 0, stream>>>(qkv, ctxs);

    // 4. out-proj + residual: x1 = x + ctx @ out_w^T + b   (BN=64)
    gemm_tile<64, 1><<<dim3(DD / 64, MM / 128), 256, 0, stream>>>(
        ctxs, wos, b_out, x, x1, nullptr, DD, 512);

    // 5. LN2 -> bf16
    ln_kernel<<<MM, 128, 0, stream>>>(x1, ln2_g, ln2_b, lnq);

    // 6. FF1 + GELU -> bf16 ffh   (BK=32 BN=128: grid 1024)
    gemm_k32<2><<<dim3(DFF / 128, MM / 128), 256, 0, stream>>>(
        lnq, w1s, b_ff1, ffh, DFF, 512);

    // 7. FF2 + residual: out = x1 + ffh @ ff_w2^T + b   (BN=64, K=2048)
    gemm_tile<64, 1><<<dim3(DD / 64, MM / 128), 256, 0, stream>>>(
        ffh, w2s, b_ff2, x1, out, nullptr, DD, 2048);
}